// Round 1
// baseline (134.110 us; speedup 1.0000x reference)
//
#include <hip/hip_runtime.h>

// Node record layout (stride 32 floats = 128B, one cache line):
//   [0..8]   A[h][j]  = sum_k vt[k][h] * Frame[k][j]   (vt = vec^T @ W)
//   [9..17]  Frame[k][j] (row-major)
//   [18..20] pF[j] = sum_k pos[k]*Frame[k][j]
//   [21..23] pos[0..2]
#define REC_STRIDE 32

__global__ void pre_node(const float* __restrict__ vec, const float* __restrict__ frame,
                         const float* __restrict__ pos, const float* __restrict__ W,
                         float* __restrict__ out, int n)
{
    int i = blockIdx.x * blockDim.x + threadIdx.x;
    if (i >= n) return;

    float w[16][3];
#pragma unroll
    for (int d = 0; d < 16; ++d) {
        w[d][0] = W[d * 3 + 0];
        w[d][1] = W[d * 3 + 1];
        w[d][2] = W[d * 3 + 2];
    }
    float vt[3][3] = {{0.f}};  // [k][h]
    const float* vp = vec + (size_t)i * 48;
#pragma unroll
    for (int d = 0; d < 16; ++d) {
        float r0 = vp[d * 3 + 0], r1 = vp[d * 3 + 1], r2 = vp[d * 3 + 2];
#pragma unroll
        for (int h = 0; h < 3; ++h) {
            vt[0][h] += r0 * w[d][h];
            vt[1][h] += r1 * w[d][h];
            vt[2][h] += r2 * w[d][h];
        }
    }
    float F[9];
#pragma unroll
    for (int j = 0; j < 9; ++j) F[j] = frame[(size_t)i * 9 + j];
    float p0 = pos[(size_t)i * 3 + 0];
    float p1 = pos[(size_t)i * 3 + 1];
    float p2 = pos[(size_t)i * 3 + 2];

    float o[24];
#pragma unroll
    for (int h = 0; h < 3; ++h)
#pragma unroll
        for (int j = 0; j < 3; ++j)
            o[h * 3 + j] = vt[0][h] * F[0 + j] + vt[1][h] * F[3 + j] + vt[2][h] * F[6 + j];
#pragma unroll
    for (int j = 0; j < 9; ++j) o[9 + j] = F[j];
#pragma unroll
    for (int j = 0; j < 3; ++j) o[18 + j] = p0 * F[j] + p1 * F[3 + j] + p2 * F[6 + j];
    o[21] = p0; o[22] = p1; o[23] = p2;

    float4* op = (float4*)(out + (size_t)i * REC_STRIDE);
#pragma unroll
    for (int q = 0; q < 6; ++q) op[q] = ((const float4*)o)[q];
}

__device__ __forceinline__ float silu_f(float x)
{
    // x * sigmoid(x); rcp is ~1ulp v_rcp_f32, fine vs 2e-2 abs threshold
    return x * __builtin_amdgcn_rcpf(1.f + __expf(-x));
}

__global__ void edge_score(const int* __restrict__ inc,
                           const float* __restrict__ fromRec, const float* __restrict__ toRec,
                           const float* __restrict__ Wa,
                           float* __restrict__ ex_out, float* __restrict__ segsum, int E)
{
    int e = blockIdx.x * blockDim.x + threadIdx.x;
    if (e >= E) return;
    int fi = inc[e];
    int ti = inc[E + e];

    float fr[24], tr[24];
    const float4* fp4 = (const float4*)(fromRec + (size_t)fi * REC_STRIDE);
    const float4* tp4 = (const float4*)(toRec + (size_t)ti * REC_STRIDE);
#pragma unroll
    for (int q = 0; q < 6; ++q) ((float4*)fr)[q] = fp4[q];
#pragma unroll
    for (int q = 0; q < 6; ++q) ((float4*)tr)[q] = tp4[q];

    float v[24];
#pragma unroll
    for (int j = 0; j < 9; ++j) v[j] = fr[j];          // fs rows h=0..2
#pragma unroll
    for (int j = 0; j < 3; ++j)                        // fs row h=3: (tpos - fpos) @ Ffrom
        v[9 + j] = tr[21] * fr[9 + j] + tr[22] * fr[12 + j] + tr[23] * fr[15 + j] - fr[18 + j];
#pragma unroll
    for (int j = 0; j < 9; ++j) v[12 + j] = tr[j];     // ts rows h=0..2
#pragma unroll
    for (int j = 0; j < 3; ++j)                        // ts row h=3: (fpos - tpos) @ Fto
        v[21 + j] = fr[21] * tr[9 + j] + fr[22] * tr[12 + j] + fr[23] * tr[15 + j] - tr[18 + j];

    float raw = 0.f;
#pragma unroll
    for (int j = 0; j < 24; ++j) raw += silu_f(v[j]) * Wa[j];

    float ex = __expf(raw);  // shift-invariant softmax: |raw| << 80, no overflow
    ex_out[e] = ex;
    atomicAdd(&segsum[fi], ex);
}

__global__ void edge_norm(const int* __restrict__ inc, const float* __restrict__ segsum,
                          float* __restrict__ out, int E)
{
    int e = blockIdx.x * blockDim.x + threadIdx.x;
    if (e >= E) return;
    out[e] = out[e] * __builtin_amdgcn_rcpf(segsum[inc[e]]);
}

// -------- fallback path (no precompute) if ws is too small ----------
__global__ void edge_direct(const int* __restrict__ inc,
                            const float* __restrict__ from_vec, const float* __restrict__ to_vec,
                            const float* __restrict__ from_frame, const float* __restrict__ to_frame,
                            const float* __restrict__ from_pos, const float* __restrict__ to_pos,
                            const float* __restrict__ Wf, const float* __restrict__ Wt,
                            const float* __restrict__ Wa,
                            float* __restrict__ ex_out, float* __restrict__ segsum, int E)
{
    int e = blockIdx.x * blockDim.x + threadIdx.x;
    if (e >= E) return;
    int fi = inc[e];
    int ti = inc[E + e];

    float fvt[3][3] = {{0.f}}, tvt[3][3] = {{0.f}};
    const float* fvp = from_vec + (size_t)fi * 48;
    const float* tvp = to_vec + (size_t)ti * 48;
#pragma unroll
    for (int d = 0; d < 16; ++d) {
#pragma unroll
        for (int h = 0; h < 3; ++h) {
            float wf = Wf[d * 3 + h], wt = Wt[d * 3 + h];
#pragma unroll
            for (int k = 0; k < 3; ++k) {
                fvt[k][h] += fvp[d * 3 + k] * wf;
                tvt[k][h] += tvp[d * 3 + k] * wt;
            }
        }
    }
    float Ff[9], Ft[9];
#pragma unroll
    for (int j = 0; j < 9; ++j) { Ff[j] = from_frame[(size_t)fi * 9 + j]; Ft[j] = to_frame[(size_t)ti * 9 + j]; }
    float pd[3];
#pragma unroll
    for (int k = 0; k < 3; ++k) pd[k] = to_pos[(size_t)ti * 3 + k] - from_pos[(size_t)fi * 3 + k];

    float v[24];
#pragma unroll
    for (int h = 0; h < 3; ++h)
#pragma unroll
        for (int j = 0; j < 3; ++j) {
            v[h * 3 + j]      = fvt[0][h] * Ff[j] + fvt[1][h] * Ff[3 + j] + fvt[2][h] * Ff[6 + j];
            v[12 + h * 3 + j] = tvt[0][h] * Ft[j] + tvt[1][h] * Ft[3 + j] + tvt[2][h] * Ft[6 + j];
        }
#pragma unroll
    for (int j = 0; j < 3; ++j) {
        v[9 + j]  =  pd[0] * Ff[j] + pd[1] * Ff[3 + j] + pd[2] * Ff[6 + j];
        v[21 + j] = -pd[0] * Ft[j] - pd[1] * Ft[3 + j] - pd[2] * Ft[6 + j];
    }
    float raw = 0.f;
#pragma unroll
    for (int j = 0; j < 24; ++j) raw += silu_f(v[j]) * Wa[j];
    float ex = __expf(raw);
    ex_out[e] = ex;
    atomicAdd(&segsum[fi], ex);
}

extern "C" void kernel_launch(void* const* d_in, const int* in_sizes, int n_in,
                              void* d_out, int out_size, void* d_ws, size_t ws_size,
                              hipStream_t stream)
{
    const float* from_vec   = (const float*)d_in[0];
    const float* to_vec     = (const float*)d_in[1];
    const float* from_frame = (const float*)d_in[2];
    const float* to_frame   = (const float*)d_in[3];
    const float* from_pos   = (const float*)d_in[4];
    const float* to_pos     = (const float*)d_in[5];
    const float* W_from     = (const float*)d_in[6];
    const float* W_to       = (const float*)d_in[7];
    const float* W_attn     = (const float*)d_in[8];
    const int*   inc        = (const int*)d_in[9];

    const int NF = in_sizes[0] / 48;   // 50000
    const int NT = in_sizes[1] / 48;   // 100000
    const int E  = in_sizes[9] / 2;    // 1600000

    float* out = (float*)d_out;
    float* ws  = (float*)d_ws;

    const size_t rec_floats = (size_t)(NF + NT) * REC_STRIDE;
    const size_t need = (rec_floats + (size_t)NF) * sizeof(float);

    const int B = 256;
    if (ws_size >= need) {
        float* fromRec = ws;
        float* toRec   = fromRec + (size_t)NF * REC_STRIDE;
        float* segsum  = toRec + (size_t)NT * REC_STRIDE;
        hipMemsetAsync(segsum, 0, (size_t)NF * sizeof(float), stream);
        pre_node<<<(NF + B - 1) / B, B, 0, stream>>>(from_vec, from_frame, from_pos, W_from, fromRec, NF);
        pre_node<<<(NT + B - 1) / B, B, 0, stream>>>(to_vec, to_frame, to_pos, W_to, toRec, NT);
        edge_score<<<(E + B - 1) / B, B, 0, stream>>>(inc, fromRec, toRec, W_attn, out, segsum, E);
        edge_norm<<<(E + B - 1) / B, B, 0, stream>>>(inc, segsum, out, E);
    } else {
        float* segsum = ws;  // only NF floats needed
        hipMemsetAsync(segsum, 0, (size_t)NF * sizeof(float), stream);
        edge_direct<<<(E + B - 1) / B, B, 0, stream>>>(inc, from_vec, to_vec, from_frame, to_frame,
                                                       from_pos, to_pos, W_from, W_to, W_attn,
                                                       out, segsum, E);
        edge_norm<<<(E + B - 1) / B, B, 0, stream>>>(inc, segsum, out, E);
    }
}

// Round 2
// 133.480 us; speedup vs baseline: 1.0047x; 1.0047x over previous
//
#include <hip/hip_runtime.h>

// Node record layout (stride 16 floats = 64B):
//   [0..8]   Frame[k][j] (row-major)
//   [9..11]  pF[j] = sum_k pos[k]*Frame[k][j]
//   [12..14] pos[0..2]
//   [15]     sA = sum_{h,j} silu(A[h][j]) * Wa[waOff + h*3 + j],
//            A[h][j] = sum_k (vec^T W)[k][h] * Frame[k][j]
#define REC_STRIDE 16

__device__ __forceinline__ float silu_f(float x)
{
    return x * __builtin_amdgcn_rcpf(1.f + __expf(-x));
}

__global__ void pre_node(const float* __restrict__ vec, const float* __restrict__ frame,
                         const float* __restrict__ pos, const float* __restrict__ W,
                         const float* __restrict__ Wa, int waOff,
                         float* __restrict__ out, int n)
{
    int i = blockIdx.x * blockDim.x + threadIdx.x;
    if (i >= n) return;

    float w[16][3];
#pragma unroll
    for (int d = 0; d < 16; ++d) {
        w[d][0] = W[d * 3 + 0];
        w[d][1] = W[d * 3 + 1];
        w[d][2] = W[d * 3 + 2];
    }
    float vt[3][3] = {{0.f}};  // [k][h]
    const float* vp = vec + (size_t)i * 48;
#pragma unroll
    for (int d = 0; d < 16; ++d) {
        float r0 = vp[d * 3 + 0], r1 = vp[d * 3 + 1], r2 = vp[d * 3 + 2];
#pragma unroll
        for (int h = 0; h < 3; ++h) {
            vt[0][h] += r0 * w[d][h];
            vt[1][h] += r1 * w[d][h];
            vt[2][h] += r2 * w[d][h];
        }
    }
    float F[9];
#pragma unroll
    for (int j = 0; j < 9; ++j) F[j] = frame[(size_t)i * 9 + j];
    float p0 = pos[(size_t)i * 3 + 0];
    float p1 = pos[(size_t)i * 3 + 1];
    float p2 = pos[(size_t)i * 3 + 2];

    float sA = 0.f;
#pragma unroll
    for (int h = 0; h < 3; ++h)
#pragma unroll
        for (int j = 0; j < 3; ++j) {
            float a = vt[0][h] * F[0 + j] + vt[1][h] * F[3 + j] + vt[2][h] * F[6 + j];
            sA += silu_f(a) * Wa[waOff + h * 3 + j];
        }

    float o[16];
#pragma unroll
    for (int j = 0; j < 9; ++j) o[j] = F[j];
#pragma unroll
    for (int j = 0; j < 3; ++j) o[9 + j] = p0 * F[j] + p1 * F[3 + j] + p2 * F[6 + j];
    o[12] = p0; o[13] = p1; o[14] = p2;
    o[15] = sA;

    float4* op = (float4*)(out + (size_t)i * REC_STRIDE);
#pragma unroll
    for (int q = 0; q < 4; ++q) op[q] = ((const float4*)o)[q];
}

__global__ void edge_score(const int* __restrict__ inc,
                           const float* __restrict__ fromRec, const float* __restrict__ toRec,
                           const float* __restrict__ Wa,
                           float* __restrict__ ex_out, float* __restrict__ segsum, int E)
{
    int e = blockIdx.x * blockDim.x + threadIdx.x;
    if (e >= E) return;
    int fi = __builtin_nontemporal_load(inc + e);
    int ti = __builtin_nontemporal_load(inc + E + e);

    float fr[16], tr[16];
    const float4* fp4 = (const float4*)(fromRec + (size_t)fi * REC_STRIDE);
    const float4* tp4 = (const float4*)(toRec + (size_t)ti * REC_STRIDE);
#pragma unroll
    for (int q = 0; q < 4; ++q) ((float4*)fr)[q] = fp4[q];
#pragma unroll
    for (int q = 0; q < 4; ++q) ((float4*)tr)[q] = tp4[q];

    // uniform weights (scalar loads)
    float wa9 = Wa[9], wa10 = Wa[10], wa11 = Wa[11];
    float wa21 = Wa[21], wa22 = Wa[22], wa23 = Wa[23];

    float raw = fr[15] + tr[15];
#pragma unroll
    for (int j = 0; j < 3; ++j) {
        // fs row h=3: (tpos - fpos) @ Ffrom_col_j  = tpos.Ff_col - pF_f
        float fd = tr[12] * fr[j] + tr[13] * fr[3 + j] + tr[14] * fr[6 + j] - fr[9 + j];
        // ts row h=3: (fpos - tpos) @ Fto_col_j    = fpos.Ft_col - pF_t
        float td = fr[12] * tr[j] + fr[13] * tr[3 + j] + fr[14] * tr[6 + j] - tr[9 + j];
        float waf = (j == 0) ? wa9 : (j == 1) ? wa10 : wa11;
        float wat = (j == 0) ? wa21 : (j == 1) ? wa22 : wa23;
        raw += silu_f(fd) * waf + silu_f(td) * wat;
    }

    float ex = __expf(raw);  // shift-invariant softmax: |raw| << 80, no overflow
    __builtin_nontemporal_store(ex, ex_out + e);
    atomicAdd(&segsum[fi], ex);
}

__global__ void edge_norm(const int* __restrict__ inc, const float* __restrict__ segsum,
                          float* __restrict__ out, int E)
{
    int e = blockIdx.x * blockDim.x + threadIdx.x;
    if (e >= E) return;
    int fi = __builtin_nontemporal_load(inc + e);
    float ex = out[e];
    __builtin_nontemporal_store(ex * __builtin_amdgcn_rcpf(segsum[fi]), out + e);
}

// -------- fallback path (no precompute) if ws is too small ----------
__global__ void edge_direct(const int* __restrict__ inc,
                            const float* __restrict__ from_vec, const float* __restrict__ to_vec,
                            const float* __restrict__ from_frame, const float* __restrict__ to_frame,
                            const float* __restrict__ from_pos, const float* __restrict__ to_pos,
                            const float* __restrict__ Wf, const float* __restrict__ Wt,
                            const float* __restrict__ Wa,
                            float* __restrict__ ex_out, float* __restrict__ segsum, int E)
{
    int e = blockIdx.x * blockDim.x + threadIdx.x;
    if (e >= E) return;
    int fi = inc[e];
    int ti = inc[E + e];

    float fvt[3][3] = {{0.f}}, tvt[3][3] = {{0.f}};
    const float* fvp = from_vec + (size_t)fi * 48;
    const float* tvp = to_vec + (size_t)ti * 48;
#pragma unroll
    for (int d = 0; d < 16; ++d) {
#pragma unroll
        for (int h = 0; h < 3; ++h) {
            float wf = Wf[d * 3 + h], wt = Wt[d * 3 + h];
#pragma unroll
            for (int k = 0; k < 3; ++k) {
                fvt[k][h] += fvp[d * 3 + k] * wf;
                tvt[k][h] += tvp[d * 3 + k] * wt;
            }
        }
    }
    float Ff[9], Ft[9];
#pragma unroll
    for (int j = 0; j < 9; ++j) { Ff[j] = from_frame[(size_t)fi * 9 + j]; Ft[j] = to_frame[(size_t)ti * 9 + j]; }
    float pd[3];
#pragma unroll
    for (int k = 0; k < 3; ++k) pd[k] = to_pos[(size_t)ti * 3 + k] - from_pos[(size_t)fi * 3 + k];

    float v[24];
#pragma unroll
    for (int h = 0; h < 3; ++h)
#pragma unroll
        for (int j = 0; j < 3; ++j) {
            v[h * 3 + j]      = fvt[0][h] * Ff[j] + fvt[1][h] * Ff[3 + j] + fvt[2][h] * Ff[6 + j];
            v[12 + h * 3 + j] = tvt[0][h] * Ft[j] + tvt[1][h] * Ft[3 + j] + tvt[2][h] * Ft[6 + j];
        }
#pragma unroll
    for (int j = 0; j < 3; ++j) {
        v[9 + j]  =  pd[0] * Ff[j] + pd[1] * Ff[3 + j] + pd[2] * Ff[6 + j];
        v[21 + j] = -pd[0] * Ft[j] - pd[1] * Ft[3 + j] - pd[2] * Ft[6 + j];
    }
    float raw = 0.f;
#pragma unroll
    for (int j = 0; j < 24; ++j) raw += silu_f(v[j]) * Wa[j];
    float ex = __expf(raw);
    ex_out[e] = ex;
    atomicAdd(&segsum[fi], ex);
}

extern "C" void kernel_launch(void* const* d_in, const int* in_sizes, int n_in,
                              void* d_out, int out_size, void* d_ws, size_t ws_size,
                              hipStream_t stream)
{
    const float* from_vec   = (const float*)d_in[0];
    const float* to_vec     = (const float*)d_in[1];
    const float* from_frame = (const float*)d_in[2];
    const float* to_frame   = (const float*)d_in[3];
    const float* from_pos   = (const float*)d_in[4];
    const float* to_pos     = (const float*)d_in[5];
    const float* W_from     = (const float*)d_in[6];
    const float* W_to       = (const float*)d_in[7];
    const float* W_attn     = (const float*)d_in[8];
    const int*   inc        = (const int*)d_in[9];

    const int NF = in_sizes[0] / 48;   // 50000
    const int NT = in_sizes[1] / 48;   // 100000
    const int E  = in_sizes[9] / 2;    // 1600000

    float* out = (float*)d_out;
    float* ws  = (float*)d_ws;

    const size_t rec_floats = (size_t)(NF + NT) * REC_STRIDE;
    const size_t need = (rec_floats + (size_t)NF) * sizeof(float);

    const int B = 256;
    if (ws_size >= need) {
        float* fromRec = ws;
        float* toRec   = fromRec + (size_t)NF * REC_STRIDE;
        float* segsum  = toRec + (size_t)NT * REC_STRIDE;
        hipMemsetAsync(segsum, 0, (size_t)NF * sizeof(float), stream);
        pre_node<<<(NF + B - 1) / B, B, 0, stream>>>(from_vec, from_frame, from_pos, W_from, W_attn, 0,  fromRec, NF);
        pre_node<<<(NT + B - 1) / B, B, 0, stream>>>(to_vec, to_frame, to_pos, W_to, W_attn, 12, toRec, NT);
        edge_score<<<(E + B - 1) / B, B, 0, stream>>>(inc, fromRec, toRec, W_attn, out, segsum, E);
        edge_norm<<<(E + B - 1) / B, B, 0, stream>>>(inc, segsum, out, E);
    } else {
        float* segsum = ws;  // only NF floats needed
        hipMemsetAsync(segsum, 0, (size_t)NF * sizeof(float), stream);
        edge_direct<<<(E + B - 1) / B, B, 0, stream>>>(inc, from_vec, to_vec, from_frame, to_frame,
                                                       from_pos, to_pos, W_from, W_to, W_attn,
                                                       out, segsum, E);
        edge_norm<<<(E + B - 1) / B, B, 0, stream>>>(inc, segsum, out, E);
    }
}